// Round 1
// baseline (1288.279 us; speedup 1.0000x reference)
//
#include <hip/hip_runtime.h>
#include <math.h>

#define NMS_THR 0.3f

__device__ __forceinline__ float fmul(float a, float b){ return __fmul_rn(a,b); }
__device__ __forceinline__ float fadd(float a, float b){ return __fadd_rn(a,b); }
__device__ __forceinline__ float fsub(float a, float b){ return __fsub_rn(a,b); }

// K1: per-row softmax max/sum + argmax + per-class regression decode. One wave per row.
__global__ __launch_bounds__(256) void k_decode(
    const float* __restrict__ prop, const float* __restrict__ reg,
    const float* __restrict__ clss, const float* __restrict__ stds,
    const int* __restrict__ imgsz,
    float* __restrict__ boxes, float* __restrict__ key,
    float* __restrict__ score, int* __restrict__ cls,
    int N, int C)
{
    int wid  = threadIdx.x >> 6;
    int lane = threadIdx.x & 63;
    int n = blockIdx.x * 4 + wid;
    if (n >= N) return;
    const float* row = clss + (long)n * C;
    float ninf = -__builtin_inff();
    float x0 = (lane < C)      ? row[lane]      : ninf;
    float x1 = (lane + 64 < C) ? row[lane + 64] : ninf;
    float m = fmaxf(x0, x1);
    for (int o = 32; o > 0; o >>= 1) m = fmaxf(m, __shfl_xor(m, o));
    float e0 = (lane < C)      ? expf(x0 - m) : 0.0f;
    float e1 = (lane + 64 < C) ? expf(x1 - m) : 0.0f;
    float s = e0 + e1;
    for (int o = 32; o > 0; o >>= 1) s += __shfl_xor(s, o);
    // argmax over exp-values (same order as probs); tie -> smallest index
    float bv; int bi;
    if (e0 >= e1) { bv = e0; bi = lane; } else { bv = e1; bi = lane + 64; }
    for (int o = 32; o > 0; o >>= 1) {
        float ov = __shfl_xor(bv, o);
        int   oi = __shfl_xor(bi, o);
        if (ov > bv || (ov == bv && oi < bi)) { bv = ov; bi = oi; }
    }
    if (lane == 0) {
        float sc = 1.0f / s;          // prob of argmax class: exp(0)/sum
        int   c  = bi;
        int   valid = (c != 0);
        float p0 = prop[n*4+0], p1 = prop[n*4+1], p2 = prop[n*4+2], p3 = prop[n*4+3];
        float w  = fsub(p2, p0), h = fsub(p3, p1);
        float cx = fadd(p0, fmul(0.5f, w));
        float cy = fadd(p1, fmul(0.5f, h));
        const float* rr = reg + (long)n * C * 4 + (long)c * 4;
        float t0 = fmul(rr[0], stds[0]);
        float t1 = fmul(rr[1], stds[1]);
        float t2 = fmul(rr[2], stds[2]);
        float t3 = fmul(rr[3], stds[3]);
        float px = fadd(cx, fmul(w, t0));
        float py = fadd(cy, fmul(h, t1));
        float pw = fmul(w, expf(t2));
        float ph = fmul(h, expf(t3));
        float hi = (float)(imgsz[0] - 1);
        float bx1 = fminf(fmaxf(fsub(px, fmul(0.5f, pw)), 0.0f), hi);
        float by1 = fminf(fmaxf(fsub(py, fmul(0.5f, ph)), 0.0f), hi);
        float bx2 = fminf(fmaxf(fadd(px, fmul(0.5f, pw)), 0.0f), hi);
        float by2 = fminf(fmaxf(fadd(py, fmul(0.5f, ph)), 0.0f), hi);
        boxes[n*4+0]=bx1; boxes[n*4+1]=by1; boxes[n*4+2]=bx2; boxes[n*4+3]=by2;
        score[n] = sc;
        cls[n]   = c;
        key[n]   = valid ? sc : ninf;
    }
}

// K2: stable descending rank sort via O(N^2) comparison; scatter sorted arrays.
__global__ __launch_bounds__(256) void k_rank(
    const float* __restrict__ key, const float* __restrict__ boxes,
    float* __restrict__ boxesSorted, float* __restrict__ areaSorted,
    float* __restrict__ keySorted, int* __restrict__ ord, int* __restrict__ rank,
    int N)
{
    extern __shared__ float lkey[];   // N floats
    for (int j = threadIdx.x; j < N; j += blockDim.x) lkey[j] = key[j];
    __syncthreads();
    int i = blockIdx.x * blockDim.x + threadIdx.x;
    if (i >= N) return;
    float ki = lkey[i];
    int r = 0;
    for (int j = 0; j < N; ++j) {
        float kj = lkey[j];
        r += (kj > ki) || (kj == ki && j < i);   // stable: earlier index first
    }
    rank[i] = r;
    ord[r]  = i;
    float b0 = boxes[i*4+0], b1 = boxes[i*4+1], b2 = boxes[i*4+2], b3 = boxes[i*4+3];
    boxesSorted[r*4+0]=b0; boxesSorted[r*4+1]=b1; boxesSorted[r*4+2]=b2; boxesSorted[r*4+3]=b3;
    areaSorted[r] = fmul(fsub(b2,b0), fsub(b3,b1));
    keySorted[r]  = ki;
}

// K3: suppression bitmask rows (sorted domain): bit j set iff j>i and IoU(i,j)>thr.
__global__ __launch_bounds__(256) void k_mask(
    const float* __restrict__ bs, const float* __restrict__ areas,
    const float* __restrict__ keySorted, unsigned long long* __restrict__ mask,
    int N, int W)
{
    int wid  = threadIdx.x >> 6;
    int lane = threadIdx.x & 63;
    int i = blockIdx.x * 4 + wid;
    if (i >= N) return;
    if (keySorted[i] == -__builtin_inff()) return;   // never kept -> row never read
    float ax1 = bs[i*4+0], ay1 = bs[i*4+1], ax2 = bs[i*4+2], ay2 = bs[i*4+3];
    float aa  = areas[i];
    int w0 = i >> 6;
    for (int w = w0; w < W; ++w) {
        int j = w*64 + lane;
        int bit = 0;
        if (j < N && j > i) {
            float bx1 = bs[j*4+0], by1 = bs[j*4+1], bx2 = bs[j*4+2], by2 = bs[j*4+3];
            float ba  = areas[j];
            float ix1 = fmaxf(ax1,bx1), iy1 = fmaxf(ay1,by1);
            float ix2 = fminf(ax2,bx2), iy2 = fminf(ay2,by2);
            float iw = fmaxf(fsub(ix2,ix1), 0.0f);
            float ih = fmaxf(fsub(iy2,iy1), 0.0f);
            float inter = fmul(iw, ih);
            float denom = fadd(fsub(fadd(aa, ba), inter), 1e-9f);  // (aa+ba)-inter+1e-9
            float iou = inter / denom;                              // IEEE f32 divide
            bit = (iou > NMS_THR) ? 1 : 0;
        }
        unsigned long long bm = __ballot(bit);
        if (lane == 0) mask[(long)i*W + w] = bm;
    }
}

// K4: serial greedy scan, single wave. removed-bitmap distributed in registers:
// lane L owns words L and 64+L.
__global__ __launch_bounds__(64) void k_scan(
    const float* __restrict__ keySorted, const unsigned long long* __restrict__ mask,
    int* __restrict__ keepSorted, int N, int W)
{
    int lane = threadIdx.x;
    for (int i = lane; i < N; i += 64) keepSorted[i] = 0;
    __syncthreads();
    unsigned long long r0 = 0ULL, r1 = 0ULL;
    float ninf = -__builtin_inff();
    for (int i = 0; i < N; ++i) {
        float k = keySorted[i];          // uniform scalar
        if (k == ninf) break;            // invalid tail: keep stays 0
        int w0 = i >> 6, b = i & 63;
        unsigned long long word = (w0 < 64) ? __shfl(r0, w0) : __shfl(r1, w0 - 64);
        if (!((word >> b) & 1ULL)) {
            if (lane == 0) keepSorted[i] = 1;
            const unsigned long long* rowp = mask + (long)i * W;
            unsigned long long m0 = (lane >= w0 && lane < W) ? rowp[lane] : 0ULL;
            int l2 = lane + 64;
            unsigned long long m1 = (l2 >= w0 && l2 < W) ? rowp[l2] : 0ULL;
            r0 |= m0; r1 |= m1;
        }
    }
}

// K5: write outputs in original order: boxes*m, score*m, float(cls*keep).
__global__ __launch_bounds__(256) void k_out(
    const float* __restrict__ boxes, const float* __restrict__ score,
    const int* __restrict__ cls, const int* __restrict__ rank,
    const int* __restrict__ keepSorted,
    float* __restrict__ out, int N)
{
    int n = blockIdx.x * blockDim.x + threadIdx.x;
    if (n >= N) return;
    int k = keepSorted[rank[n]];
    float m = (float)k;
    out[n*4+0] = boxes[n*4+0]*m;
    out[n*4+1] = boxes[n*4+1]*m;
    out[n*4+2] = boxes[n*4+2]*m;
    out[n*4+3] = boxes[n*4+3]*m;
    out[(long)N*4 + n] = score[n]*m;
    out[(long)N*5 + n] = (float)(cls[n] * k);
}

extern "C" void kernel_launch(void* const* d_in, const int* in_sizes, int n_in,
                              void* d_out, int out_size, void* d_ws, size_t ws_size,
                              hipStream_t stream) {
    const float* prop = (const float*)d_in[0];
    const float* reg  = (const float*)d_in[1];
    const float* clss = (const float*)d_in[2];
    const float* stds = (const float*)d_in[3];
    const int*   img  = (const int*)d_in[4];

    int N = in_sizes[0] / 4;
    int C = in_sizes[2] / N;
    int W = (N + 63) / 64;

    char* ws = (char*)d_ws;
    size_t off = 0;
    float* boxes       = (float*)(ws + off); off += (size_t)N*4*sizeof(float);
    float* key         = (float*)(ws + off); off += (size_t)N*sizeof(float);
    float* score       = (float*)(ws + off); off += (size_t)N*sizeof(float);
    int*   cls         = (int*)  (ws + off); off += (size_t)N*sizeof(int);
    int*   rank        = (int*)  (ws + off); off += (size_t)N*sizeof(int);
    float* boxesSorted = (float*)(ws + off); off += (size_t)N*4*sizeof(float);
    float* areaSorted  = (float*)(ws + off); off += (size_t)N*sizeof(float);
    float* keySorted   = (float*)(ws + off); off += (size_t)N*sizeof(float);
    int*   ord         = (int*)  (ws + off); off += (size_t)N*sizeof(int);
    int*   keepSorted  = (int*)  (ws + off); off += (size_t)N*sizeof(int);
    off = (off + 7) & ~(size_t)7;
    unsigned long long* mask = (unsigned long long*)(ws + off);
    off += (size_t)N * W * sizeof(unsigned long long);
    (void)ord; (void)ws_size; (void)out_size; (void)n_in;

    int rowBlocks = (N + 3) / 4;
    int thrBlocks = (N + 255) / 256;

    k_decode<<<rowBlocks, 256, 0, stream>>>(prop, reg, clss, stds, img,
                                            boxes, key, score, cls, N, C);
    k_rank<<<thrBlocks, 256, (size_t)N*sizeof(float), stream>>>(key, boxes,
                                            boxesSorted, areaSorted, keySorted, ord, rank, N);
    k_mask<<<rowBlocks, 256, 0, stream>>>(boxesSorted, areaSorted, keySorted, mask, N, W);
    k_scan<<<1, 64, 0, stream>>>(keySorted, mask, keepSorted, N, W);
    k_out<<<thrBlocks, 256, 0, stream>>>(boxes, score, cls, rank, keepSorted,
                                         (float*)d_out, N);
}

// Round 2
// 319.955 us; speedup vs baseline: 4.0264x; 4.0264x over previous
//
#include <hip/hip_runtime.h>
#include <math.h>

#define NMS_THR 0.3f

__device__ __forceinline__ float fmul(float a, float b){ return __fmul_rn(a,b); }
__device__ __forceinline__ float fadd(float a, float b){ return __fadd_rn(a,b); }
__device__ __forceinline__ float fsub(float a, float b){ return __fsub_rn(a,b); }

// K1: per-row softmax max/sum + argmax + per-class regression decode. One wave per row.
__global__ __launch_bounds__(256) void k_decode(
    const float* __restrict__ prop, const float* __restrict__ reg,
    const float* __restrict__ clss, const float* __restrict__ stds,
    const int* __restrict__ imgsz,
    float* __restrict__ boxes, float* __restrict__ key,
    float* __restrict__ score, int* __restrict__ cls,
    int N, int C)
{
    int wid  = threadIdx.x >> 6;
    int lane = threadIdx.x & 63;
    int n = blockIdx.x * 4 + wid;
    if (n >= N) return;
    const float* row = clss + (long)n * C;
    float ninf = -__builtin_inff();
    float x0 = (lane < C)      ? row[lane]      : ninf;
    float x1 = (lane + 64 < C) ? row[lane + 64] : ninf;
    float m = fmaxf(x0, x1);
    for (int o = 32; o > 0; o >>= 1) m = fmaxf(m, __shfl_xor(m, o));
    float e0 = (lane < C)      ? expf(x0 - m) : 0.0f;
    float e1 = (lane + 64 < C) ? expf(x1 - m) : 0.0f;
    float s = e0 + e1;
    for (int o = 32; o > 0; o >>= 1) s += __shfl_xor(s, o);
    float bv; int bi;
    if (e0 >= e1) { bv = e0; bi = lane; } else { bv = e1; bi = lane + 64; }
    for (int o = 32; o > 0; o >>= 1) {
        float ov = __shfl_xor(bv, o);
        int   oi = __shfl_xor(bi, o);
        if (ov > bv || (ov == bv && oi < bi)) { bv = ov; bi = oi; }
    }
    if (lane == 0) {
        float sc = 1.0f / s;
        int   c  = bi;
        int   valid = (c != 0);
        float p0 = prop[n*4+0], p1 = prop[n*4+1], p2 = prop[n*4+2], p3 = prop[n*4+3];
        float w  = fsub(p2, p0), h = fsub(p3, p1);
        float cx = fadd(p0, fmul(0.5f, w));
        float cy = fadd(p1, fmul(0.5f, h));
        const float* rr = reg + (long)n * C * 4 + (long)c * 4;
        float t0 = fmul(rr[0], stds[0]);
        float t1 = fmul(rr[1], stds[1]);
        float t2 = fmul(rr[2], stds[2]);
        float t3 = fmul(rr[3], stds[3]);
        float px = fadd(cx, fmul(w, t0));
        float py = fadd(cy, fmul(h, t1));
        float pw = fmul(w, expf(t2));
        float ph = fmul(h, expf(t3));
        float hi = (float)(imgsz[0] - 1);
        float bx1 = fminf(fmaxf(fsub(px, fmul(0.5f, pw)), 0.0f), hi);
        float by1 = fminf(fmaxf(fsub(py, fmul(0.5f, ph)), 0.0f), hi);
        float bx2 = fminf(fmaxf(fadd(px, fmul(0.5f, pw)), 0.0f), hi);
        float by2 = fminf(fmaxf(fadd(py, fmul(0.5f, ph)), 0.0f), hi);
        boxes[n*4+0]=bx1; boxes[n*4+1]=by1; boxes[n*4+2]=bx2; boxes[n*4+3]=by2;
        score[n] = sc;
        cls[n]   = c;
        key[n]   = valid ? sc : ninf;
    }
}

// K2: stable descending rank sort. 64 rows/block, 4 j-strips of 256 threads.
// Block 0 additionally computes nValid (count of keys != -inf).
__global__ __launch_bounds__(256) void k_rank(
    const float* __restrict__ key, const float* __restrict__ boxes,
    float* __restrict__ boxesSorted, float* __restrict__ areaSorted,
    float* __restrict__ keySorted, int* __restrict__ rank,
    int* __restrict__ nValidPtr, int N)
{
    extern __shared__ float lkey[];     // N floats
    __shared__ int part[256];
    int tid = threadIdx.x;
    for (int j = tid; j < N; j += 256) lkey[j] = key[j];
    __syncthreads();

    int i = blockIdx.x * 64 + (tid & 63);
    int s = tid >> 6;
    int Q = (N + 3) >> 2;
    int r_part = 0;
    if (i < N) {
        float ki = lkey[i];
        int j0 = s * Q, j1 = min(N, j0 + Q);
        for (int j = j0; j < j1; ++j) {
            float kj = lkey[j];
            r_part += (kj > ki) || (kj == ki && j < i);   // stable
        }
    }
    part[tid] = r_part;
    __syncthreads();

    if (tid < 64 && i < N) {
        int r = part[tid] + part[tid+64] + part[tid+128] + part[tid+192];
        float ki = lkey[i];
        rank[i] = r;
        float b0 = boxes[i*4+0], b1 = boxes[i*4+1], b2 = boxes[i*4+2], b3 = boxes[i*4+3];
        boxesSorted[r*4+0]=b0; boxesSorted[r*4+1]=b1; boxesSorted[r*4+2]=b2; boxesSorted[r*4+3]=b3;
        areaSorted[r] = fmul(fsub(b2,b0), fsub(b3,b1));
        keySorted[r]  = ki;
    }

    if (blockIdx.x == 0) {
        __syncthreads();
        float ninf = -__builtin_inff();
        int inv = 0;
        for (int j = tid; j < N; j += 256) inv += (lkey[j] == ninf);
        part[tid] = inv;
        __syncthreads();
        if (tid == 0) {
            int t = 0;
            for (int q = 0; q < 256; ++q) t += part[q];
            nValidPtr[0] = N - t;
        }
    }
}

// K3: suppression bitmask, TRANSPOSED layout: maskT[w*N + i] = word w of row i.
// bit j-of-word set iff j>i and IoU(i,j)>thr (sorted domain).
__global__ __launch_bounds__(256) void k_mask(
    const float* __restrict__ bs, const float* __restrict__ areas,
    const float* __restrict__ keySorted, unsigned long long* __restrict__ maskT,
    int N, int W)
{
    int wid  = threadIdx.x >> 6;
    int lane = threadIdx.x & 63;
    int i = blockIdx.x * 4 + wid;
    if (i >= N) return;
    if (keySorted[i] == -__builtin_inff()) return;   // invalid row: never read
    float ax1 = bs[i*4+0], ay1 = bs[i*4+1], ax2 = bs[i*4+2], ay2 = bs[i*4+3];
    float aa  = areas[i];
    int w0 = i >> 6;
    for (int w = w0; w < W; ++w) {
        int j = w*64 + lane;
        int bit = 0;
        if (j < N && j > i) {
            float bx1 = bs[j*4+0], by1 = bs[j*4+1], bx2 = bs[j*4+2], by2 = bs[j*4+3];
            float ba  = areas[j];
            float ix1 = fmaxf(ax1,bx1), iy1 = fmaxf(ay1,by1);
            float ix2 = fminf(ax2,bx2), iy2 = fminf(ay2,by2);
            float iw = fmaxf(fsub(ix2,ix1), 0.0f);
            float ih = fmaxf(fsub(iy2,iy1), 0.0f);
            float inter = fmul(iw, ih);
            float denom = fadd(fsub(fadd(aa, ba), inter), 1e-9f);
            float iou = inter / denom;
            bit = (iou > NMS_THR) ? 1 : 0;
        }
        unsigned long long bm = __ballot(bit);
        if (lane == 0) maskT[(long)w*N + i] = bm;
    }
}

// K4: chunked greedy scan, single wave. removed-bitmap distributed: lane L owns
// words L and 64+L. Per 64-row chunk: in-register resolve over kept rows only,
// then batched OR of kept rows' cross-chunk mask words.
__global__ __launch_bounds__(64) void k_scan(
    const unsigned long long* __restrict__ maskT, const int* __restrict__ nValidPtr,
    int* __restrict__ keepSorted, int N, int W)
{
    int lane = threadIdx.x;
    for (int i = lane; i < N; i += 64) keepSorted[i] = 0;
    int nValid = nValidPtr[0];
    int nChunks = (nValid + 63) >> 6;
    unsigned long long r0 = 0ULL, r1 = 0ULL;
    int w1 = lane + 64;

    // diag word of chunk 0
    unsigned long long D = (lane < nValid) ? maskT[lane] : 0ULL;

    for (int c = 0; c < nChunks; ++c) {
        int base = c << 6;
        // prefetch next chunk's diagonal word (coalesced, off critical path)
        unsigned long long Dn = 0ULL;
        int nrow = base + 64 + lane;
        if (c + 1 < nChunks && nrow < nValid)
            Dn = maskT[(long)(c+1)*N + nrow];

        unsigned long long inc = (c < 64) ? __shfl(r0, c) : __shfl(r1, c - 64);
        int nv = nValid - base;
        unsigned long long validBits = (nv >= 64) ? ~0ULL
                                     : ((1ULL << nv) - 1ULL);
        unsigned long long cand = validBits & ~inc;
        unsigned long long keepM = 0ULL;
        while (cand) {
            int a = __builtin_ctzll(cand);
            keepM |= (1ULL << a);
            unsigned long long Da = __shfl(D, a);
            cand &= ~(1ULL << a);
            cand &= ~Da;
        }
        // write keep bits for this chunk
        if (base + lane < N) keepSorted[base + lane] = (int)((keepM >> lane) & 1ULL);

        // batched cross-chunk OR: 8 kept rows per batch -> 16 independent loads
        unsigned long long kb = keepM;
#define GRAB(v0, v1) \
        { unsigned long long _m0 = 0ULL, _m1 = 0ULL; \
          if (kb) { int _a = __builtin_ctzll(kb); kb &= kb - 1ULL; int _row = base + _a; \
            _m0 = (lane > c) ? maskT[(long)lane*N + _row] : 0ULL; \
            _m1 = (w1 > c && w1 < W) ? maskT[(long)w1*N + _row] : 0ULL; } \
          v0 = _m0; v1 = _m1; }
        while (kb) {
            unsigned long long a0,a1,b0,b1,c0,c1,d0,d1,e0,e1,f0,f1,g0,g1,h0,h1;
            GRAB(a0,a1) GRAB(b0,b1) GRAB(c0,c1) GRAB(d0,d1)
            GRAB(e0,e1) GRAB(f0,f1) GRAB(g0,g1) GRAB(h0,h1)
            r0 |= (a0|b0) | (c0|d0) | ((e0|f0) | (g0|h0));
            r1 |= (a1|b1) | (c1|d1) | ((e1|f1) | (g1|h1));
        }
#undef GRAB
        D = Dn;
    }
}

// K5: write outputs in original order: boxes*m, score*m, float(cls*keep).
__global__ __launch_bounds__(256) void k_out(
    const float* __restrict__ boxes, const float* __restrict__ score,
    const int* __restrict__ cls, const int* __restrict__ rank,
    const int* __restrict__ keepSorted,
    float* __restrict__ out, int N)
{
    int n = blockIdx.x * blockDim.x + threadIdx.x;
    if (n >= N) return;
    int k = keepSorted[rank[n]];
    float m = (float)k;
    out[n*4+0] = boxes[n*4+0]*m;
    out[n*4+1] = boxes[n*4+1]*m;
    out[n*4+2] = boxes[n*4+2]*m;
    out[n*4+3] = boxes[n*4+3]*m;
    out[(long)N*4 + n] = score[n]*m;
    out[(long)N*5 + n] = (float)(cls[n] * k);
}

extern "C" void kernel_launch(void* const* d_in, const int* in_sizes, int n_in,
                              void* d_out, int out_size, void* d_ws, size_t ws_size,
                              hipStream_t stream) {
    const float* prop = (const float*)d_in[0];
    const float* reg  = (const float*)d_in[1];
    const float* clss = (const float*)d_in[2];
    const float* stds = (const float*)d_in[3];
    const int*   img  = (const int*)d_in[4];

    int N = in_sizes[0] / 4;
    int C = in_sizes[2] / N;
    int W = (N + 63) / 64;

    char* ws = (char*)d_ws;
    size_t off = 0;
    float* boxes       = (float*)(ws + off); off += (size_t)N*4*sizeof(float);
    float* key         = (float*)(ws + off); off += (size_t)N*sizeof(float);
    float* score       = (float*)(ws + off); off += (size_t)N*sizeof(float);
    int*   cls         = (int*)  (ws + off); off += (size_t)N*sizeof(int);
    int*   rank        = (int*)  (ws + off); off += (size_t)N*sizeof(int);
    float* boxesSorted = (float*)(ws + off); off += (size_t)N*4*sizeof(float);
    float* areaSorted  = (float*)(ws + off); off += (size_t)N*sizeof(float);
    float* keySorted   = (float*)(ws + off); off += (size_t)N*sizeof(float);
    int*   keepSorted  = (int*)  (ws + off); off += (size_t)N*sizeof(int);
    int*   nValid      = (int*)  (ws + off); off += sizeof(int);
    off = (off + 7) & ~(size_t)7;
    unsigned long long* maskT = (unsigned long long*)(ws + off);
    off += (size_t)N * W * sizeof(unsigned long long);
    (void)ws_size; (void)out_size; (void)n_in;

    int rowBlocks  = (N + 3) / 4;
    int thrBlocks  = (N + 255) / 256;
    int rankBlocks = (N + 63) / 64;

    k_decode<<<rowBlocks, 256, 0, stream>>>(prop, reg, clss, stds, img,
                                            boxes, key, score, cls, N, C);
    k_rank<<<rankBlocks, 256, (size_t)N*sizeof(float), stream>>>(key, boxes,
                                            boxesSorted, areaSorted, keySorted, rank, nValid, N);
    k_mask<<<rowBlocks, 256, 0, stream>>>(boxesSorted, areaSorted, keySorted, maskT, N, W);
    k_scan<<<1, 64, 0, stream>>>(maskT, nValid, keepSorted, N, W);
    k_out<<<thrBlocks, 256, 0, stream>>>(boxes, score, cls, rank, keepSorted,
                                         (float*)d_out, N);
}